// Round 1
// baseline (1036.679 us; speedup 1.0000x reference)
//
#include <hip/hip_runtime.h>

// Problem constants (B=2, H=16, S=2048, D=64, NUM_EMB=8192)
#define BH     32
#define S_LEN  2048
#define D_DIM  64
#define NTAU   33      // u-tiles per i-tile: tau in [-1, 31]
#define LDSTR  72      // LDS row stride in halves (64 + 8 pad -> 144B, breaks bank aliasing)

typedef _Float16 half8 __attribute__((ext_vector_type(8)));
typedef _Float16 half4 __attribute__((ext_vector_type(4)));
typedef float    f32x4 __attribute__((ext_vector_type(4)));

// out[b,h,i,j] = scores[b,h,i,j] + sum_d q[b,h,i,d] * emb[j-i+4096, d]
// Skewed-space tiling: block = (bh, i-tile ti, tau). i0 = 64*ti, u0 = 64*tau - i0.
// Tile element (ii,uu): i = i0+ii, emb row = u0+uu+4096, j = i+u = 64*tau + ii + uu.
// Coverage: for any (i,j), tau = floor((j - (i&63))/64) in [-1,31] — exactly once.
__global__ __launch_bounds__(256, 4)
void relpos_mfma_kernel(const float* __restrict__ q,
                        const float* __restrict__ sc,
                        const float* __restrict__ emb,
                        float* __restrict__ out)
{
    __shared__ _Float16 Alds[64 * LDSTR];   // Q tile, f16
    __shared__ _Float16 Elds[64 * LDSTR];   // emb tile, f16

    const int tid = threadIdx.x;
    int bid = blockIdx.x;
    const int t   = bid % NTAU;  bid /= NTAU;
    const int ti  = bid % 32;
    const int bh  = bid / 32;
    const int tau = t - 1;
    const int i0  = ti * 64;
    const int r0  = 64 * tau - i0 + 4096;   // first emb row; in [2048, 6080] always

    // ---- stage Q and E tiles (fp32 -> f16), fully coalesced float4 loads ----
    const float* qbase = q   + ((size_t)bh * S_LEN + i0) * D_DIM;
    const float* ebase = emb + (size_t)r0 * D_DIM;
    #pragma unroll
    for (int k = 0; k < 4; ++k) {
        int f   = tid + k * 256;       // float4 index 0..1023
        int row = f >> 4;              // 16 float4 per 64-elem row
        int c4  = (f & 15) * 4;
        f32x4 vq = *(const f32x4*)(qbase + row * D_DIM + c4);
        f32x4 ve = *(const f32x4*)(ebase + row * D_DIM + c4);
        half4 hq, he;
        hq.x = (_Float16)vq.x; hq.y = (_Float16)vq.y;
        hq.z = (_Float16)vq.z; hq.w = (_Float16)vq.w;
        he.x = (_Float16)ve.x; he.y = (_Float16)ve.y;
        he.z = (_Float16)ve.z; he.w = (_Float16)ve.w;
        *(half4*)&Alds[row * LDSTR + c4] = hq;
        *(half4*)&Elds[row * LDSTR + c4] = he;
    }
    __syncthreads();

    const int wave = tid >> 6;     // 4 waves: rows [16w, 16w+16)
    const int lane = tid & 63;
    const int lrow = lane & 15;
    const int quad = lane >> 4;

    // ---- prefetch scores (issue HBM reads before MFMA so latency hides) ----
    // C/D layout (16x16x32): col = lane&15 (+16c), row = quad*4 + reg (+16w)
    const int ii_base = wave * 16 + quad * 4;
    float    s_pre[4][4];
    unsigned idxs [4][4];
    bool     valid[4][4];
    #pragma unroll
    for (int c = 0; c < 4; ++c) {
        int uu = c * 16 + lrow;
        #pragma unroll
        for (int r = 0; r < 4; ++r) {
            int ii = ii_base + r;
            int j  = tau * 64 + ii + uu;          // i0 cancels out
            int i  = i0 + ii;
            bool v = (unsigned)j < (unsigned)S_LEN;
            unsigned idx = ((unsigned)(bh * S_LEN + i)) * (unsigned)S_LEN
                         + (unsigned)(v ? j : 0);
            valid[c][r] = v;
            idxs [c][r] = idx;
            s_pre[c][r] = v ? sc[idx] : 0.0f;
        }
    }

    // ---- fragments + MFMA: C[m=i-row][n=u-col] = sum_k A[m][k]*E[n][k] ----
    // A-frag: A[m=lane&15][k=quad*8+j]; B-frag: B[k=quad*8+j][n=lane&15] = E[n][k]
    const _Float16* arow = &Alds[(wave * 16 + lrow) * LDSTR + quad * 8];
    half8 a0 = *(const half8*)(arow);        // k in [0,32)
    half8 a1 = *(const half8*)(arow + 32);   // k in [32,64)

    f32x4 acc[4];
    #pragma unroll
    for (int c = 0; c < 4; ++c) {
        const _Float16* brow = &Elds[(c * 16 + lrow) * LDSTR + quad * 8];
        half8 b0 = *(const half8*)(brow);
        half8 b1 = *(const half8*)(brow + 32);
        f32x4 z = {0.0f, 0.0f, 0.0f, 0.0f};
        z = __builtin_amdgcn_mfma_f32_16x16x32_f16(a0, b0, z, 0, 0, 0);
        z = __builtin_amdgcn_mfma_f32_16x16x32_f16(a1, b1, z, 0, 0, 0);
        acc[c] = z;
    }

    // ---- epilogue: add scores, store (16-lane-contiguous 64B segments) ----
    #pragma unroll
    for (int c = 0; c < 4; ++c) {
        #pragma unroll
        for (int r = 0; r < 4; ++r) {
            if (valid[c][r]) {
                out[idxs[c][r]] = s_pre[c][r] + acc[c][r];
            }
        }
    }
}

extern "C" void kernel_launch(void* const* d_in, const int* in_sizes, int n_in,
                              void* d_out, int out_size, void* d_ws, size_t ws_size,
                              hipStream_t stream) {
    const float* q   = (const float*)d_in[0];   // [B,H,S,D] fp32
    const float* sc  = (const float*)d_in[1];   // [B,H,S,S] fp32
    const float* emb = (const float*)d_in[2];   // [NUM_EMB,D] fp32
    float* out = (float*)d_out;                 // [B,H,S,S] fp32

    dim3 grid(BH * 32 * NTAU);   // 33,792 blocks
    relpos_mfma_kernel<<<grid, 256, 0, stream>>>(q, sc, emb, out);
}